// Round 1
// baseline (4479.840 us; speedup 1.0000x reference)
//
#include <hip/hip_runtime.h>

#define HID 96
#define B_GRAPHS 16384
#define NN (B_GRAPHS * 5)          // 81920 nodes
#define NE (B_GRAPHS * 5 * 4)      // 327680 edges

__device__ __forceinline__ float sp_f(float x) {
    // softplus = max(x,0) + log1p(exp(-|x|))  (matches jax.nn.softplus)
    return fmaxf(x, 0.0f) + log1pf(expf(-fabsf(x)));
}

// Generic tiled MLP layer: out[r][c] = sum_k in(r,k) * W[k][c]
// 256 threads; tx = t&31 owns cols c0..c0+2 (c0=tx*3), ty = t>>5 owns RPT rows.
// RPT=4 -> 32 rows, RPT=1 -> 8 rows. Weights staged in 32xHID LDS chunks.
template <int RPT, class InF>
__device__ __forceinline__ void mlp_tile(const float* __restrict__ W, int K,
                                         float* __restrict__ wbuf, InF inf,
                                         int t, float acc[RPT][3]) {
    const int tx = t & 31;
    const int ty = t >> 5;
    const int c0 = tx * 3;
#pragma unroll
    for (int i = 0; i < RPT; i++) {
        acc[i][0] = 0.f; acc[i][1] = 0.f; acc[i][2] = 0.f;
    }
    for (int k0 = 0; k0 < K; k0 += 32) {
        __syncthreads();  // protect wbuf reuse + publish caller's LDS writes
        for (int idx = t; idx < 32 * HID; idx += 256)
            wbuf[idx] = W[(size_t)(k0 + (idx / HID)) * HID + (idx % HID)];
        __syncthreads();
#pragma unroll 8
        for (int kk = 0; kk < 32; kk++) {
            float w0 = wbuf[kk * HID + c0 + 0];
            float w1 = wbuf[kk * HID + c0 + 1];
            float w2 = wbuf[kk * HID + c0 + 2];
#pragma unroll
            for (int i = 0; i < RPT; i++) {
                float xv = inf(ty * RPT + i, k0 + kk);
                acc[i][0] = fmaf(xv, w0, acc[i][0]);
                acc[i][1] = fmaf(xv, w1, acc[i][1]);
                acc[i][2] = fmaf(xv, w2, acc[i][2]);
            }
        }
    }
}

// ---------------- Kernel 1: edge_mlp -> ef (stored into d_out ef2 region) ----
__global__ __launch_bounds__(256) void k_edge_mlp(
    const float* __restrict__ h, const int* __restrict__ eic,
    const float* __restrict__ ea, const float* __restrict__ ew1,
    const float* __restrict__ eb1, const float* __restrict__ ew2,
    const float* __restrict__ eb2, float* __restrict__ efg) {
    __shared__ float xs[32 * 288];
    __shared__ float wbuf[32 * HID];
    __shared__ float ef1[32 * HID];
    const int t = threadIdx.x;
    const int e0 = blockIdx.x * 32;

    for (int idx = t; idx < 32 * 288; idx += 256) {
        int r = idx / 288, k = idx % 288;
        int e = e0 + r;
        float v;
        if (k < 96)       v = h[(size_t)(e >> 2) * 96 + k];
        else if (k < 192) v = h[(size_t)eic[e] * 96 + (k - 96)];
        else              v = ea[(size_t)e * 96 + (k - 192)];
        xs[idx] = v;
    }
    float acc[4][3];
    mlp_tile<4>(ew1, 288, wbuf, [&](int r, int k) { return xs[r * 288 + k]; }, t, acc);
    {
        const int tx = t & 31, ty = t >> 5, c0 = tx * 3;
#pragma unroll
        for (int i = 0; i < 4; i++)
#pragma unroll
            for (int j = 0; j < 3; j++)
                ef1[(ty * 4 + i) * 96 + c0 + j] = sp_f(acc[i][j] + eb1[c0 + j]);
    }
    mlp_tile<4>(ew2, 96, wbuf, [&](int r, int k) { return ef1[r * 96 + k]; }, t, acc);
    {
        const int tx = t & 31, ty = t >> 5, c0 = tx * 3;
#pragma unroll
        for (int i = 0; i < 4; i++)
#pragma unroll
            for (int j = 0; j < 3; j++)
                efg[(size_t)(e0 + ty * 4 + i) * 96 + c0 + j] =
                    sp_f(acc[i][j] + eb2[c0 + j]);
    }
}

// ---------------- Kernel 2: attention + node model -> hn ---------------------
__global__ __launch_bounds__(256) void k_attn_node(
    const float* __restrict__ h, const float* __restrict__ efg,
    const float* __restrict__ qw, const float* __restrict__ qb,
    const float* __restrict__ kw, const float* __restrict__ kb,
    const float* __restrict__ vw, const float* __restrict__ vb,
    const float* __restrict__ nw1, const float* __restrict__ nb1,
    const float* __restrict__ nw2, const float* __restrict__ nb2,
    const float* __restrict__ g1, const float* __restrict__ be1,
    const float* __restrict__ g2, const float* __restrict__ be2,
    float* __restrict__ hng) {
    __shared__ float hs[8 * 96];
    __shared__ float efs[32 * 96];
    __shared__ float wbuf[32 * HID];
    __shared__ float khb[32 * 96];   // kh, later reused for vh
    __shared__ float qh[8 * 96];
    __shared__ float aggn[8 * 96];
    __shared__ float t1b[8 * 96];
    __shared__ float sc[32 * 3];     // scores, then attention weights
    const int t = threadIdx.x;
    const int n0 = blockIdx.x * 8;
    const int e0 = n0 * 4;

    for (int idx = t; idx < 8 * 96; idx += 256) hs[idx] = h[(size_t)n0 * 96 + idx];
    for (int idx = t; idx < 32 * 96; idx += 256) efs[idx] = efg[(size_t)e0 * 96 + idx];

    float acc1[1][3];
    // q projection (rows = 8 nodes)
    mlp_tile<1>(qw, 96, wbuf, [&](int r, int k) { return hs[r * 96 + k]; }, t, acc1);
    {
        const int tx = t & 31, ty = t >> 5, c0 = tx * 3;
#pragma unroll
        for (int j = 0; j < 3; j++) qh[ty * 96 + c0 + j] = acc1[0][j] + qb[c0 + j];
    }
    float acc[4][3];
    // k projection over concat[h[row], ef] (rows = 32 edges)
    mlp_tile<4>(kw, 192, wbuf,
                [&](int r, int k) {
                    return k < 96 ? hs[(r >> 2) * 96 + k] : efs[r * 96 + (k - 96)];
                },
                t, acc);
    {
        const int tx = t & 31, ty = t >> 5, c0 = tx * 3;
#pragma unroll
        for (int i = 0; i < 4; i++)
#pragma unroll
            for (int j = 0; j < 3; j++)
                khb[(ty * 4 + i) * 96 + c0 + j] = acc[i][j] + kb[c0 + j];
    }
    __syncthreads();
    // scores: one thread per (edge, head)
    if (t < 96) {
        int el = t / 3, hd = t % 3;
        const float* qp = &qh[(el >> 2) * 96 + hd * 32];
        const float* kp = &khb[el * 96 + hd * 32];
        float s = 0.f;
#pragma unroll
        for (int dd = 0; dd < 32; dd++) s = fmaf(qp[dd], kp[dd], s);
        sc[el * 3 + hd] = s * 0.17677669529663687f;  // 1/sqrt(32)
    }
    __syncthreads();
    // softmax over the 4 edges of each (node, head)
    if (t < 24) {
        int nd = t / 3, hd = t % 3;
        float v0 = sc[(nd * 4 + 0) * 3 + hd], v1 = sc[(nd * 4 + 1) * 3 + hd];
        float v2 = sc[(nd * 4 + 2) * 3 + hd], v3 = sc[(nd * 4 + 3) * 3 + hd];
        float m = fmaxf(fmaxf(v0, v1), fmaxf(v2, v3));
        float p0 = expf(v0 - m), p1 = expf(v1 - m), p2 = expf(v2 - m), p3 = expf(v3 - m);
        float inv = 1.f / (p0 + p1 + p2 + p3);
        sc[(nd * 4 + 0) * 3 + hd] = p0 * inv;
        sc[(nd * 4 + 1) * 3 + hd] = p1 * inv;
        sc[(nd * 4 + 2) * 3 + hd] = p2 * inv;
        sc[(nd * 4 + 3) * 3 + hd] = p3 * inv;
    }
    // v projection (rows = 32 edges) -> reuse khb (its readers finished above;
    // mlp_tile's leading __syncthreads orders the reuse)
    mlp_tile<4>(vw, 96, wbuf, [&](int r, int k) { return efs[r * 96 + k]; }, t, acc);
    {
        const int tx = t & 31, ty = t >> 5, c0 = tx * 3;
#pragma unroll
        for (int i = 0; i < 4; i++)
#pragma unroll
            for (int j = 0; j < 3; j++)
                khb[(ty * 4 + i) * 96 + c0 + j] = acc[i][j] + vb[c0 + j];
    }
    __syncthreads();
    // agg = sum_k attw * vh, then LayerNorm(g1,be1). ty = node, tx covers cols.
    {
        const int tx = t & 31, ty = t >> 5, c0 = tx * 3;
        float av[3];
#pragma unroll
        for (int j = 0; j < 3; j++) {
            int c = c0 + j, hd = c >> 5;
            float s = 0.f;
#pragma unroll
            for (int k = 0; k < 4; k++)
                s = fmaf(sc[(ty * 4 + k) * 3 + hd], khb[(ty * 4 + k) * 96 + c], s);
            av[j] = s;
        }
        float ps = av[0] + av[1] + av[2];
        float ps2 = av[0] * av[0] + av[1] * av[1] + av[2] * av[2];
        for (int m = 1; m < 32; m <<= 1) {
            ps += __shfl_xor(ps, m);
            ps2 += __shfl_xor(ps2, m);
        }
        float mu = ps * (1.f / 96.f);
        float var = ps2 * (1.f / 96.f) - mu * mu;
        float rs = rsqrtf(var + 1e-5f);
#pragma unroll
        for (int j = 0; j < 3; j++) {
            int c = c0 + j;
            aggn[ty * 96 + c] = (av[j] - mu) * rs * g1[c] + be1[c];
        }
    }
    // node MLP: sp(concat[h, aggn] @ nw1 + nb1) @ nw2 + nb2, residual, LN2
    mlp_tile<1>(nw1, 192, wbuf,
                [&](int r, int k) {
                    return k < 96 ? hs[r * 96 + k] : aggn[r * 96 + (k - 96)];
                },
                t, acc1);
    {
        const int tx = t & 31, ty = t >> 5, c0 = tx * 3;
#pragma unroll
        for (int j = 0; j < 3; j++)
            t1b[ty * 96 + c0 + j] = sp_f(acc1[0][j] + nb1[c0 + j]);
    }
    mlp_tile<1>(nw2, 96, wbuf, [&](int r, int k) { return t1b[r * 96 + k]; }, t, acc1);
    {
        const int tx = t & 31, ty = t >> 5, c0 = tx * 3;
        float xv[3];
#pragma unroll
        for (int j = 0; j < 3; j++)
            xv[j] = acc1[0][j] + nb2[c0 + j] + hs[ty * 96 + c0 + j];
        float ps = xv[0] + xv[1] + xv[2];
        float ps2 = xv[0] * xv[0] + xv[1] * xv[1] + xv[2] * xv[2];
        for (int m = 1; m < 32; m <<= 1) {
            ps += __shfl_xor(ps, m);
            ps2 += __shfl_xor(ps2, m);
        }
        float mu = ps * (1.f / 96.f);
        float var = ps2 * (1.f / 96.f) - mu * mu;
        float rs = rsqrtf(var + 1e-5f);
#pragma unroll
        for (int j = 0; j < 3; j++) {
            int c = c0 + j;
            hng[(size_t)(n0 + ty) * 96 + c] = (xv[j] - mu) * rs * g2[c] + be2[c];
        }
    }
}

// ------------- Kernel 3: edge enhance (ef2) + coord MLP + acc ----------------
__global__ __launch_bounds__(256) void k_enhance_coord(
    const float* __restrict__ hng, const int* __restrict__ eic,
    const float* __restrict__ ea, const float* __restrict__ cp,
    const float* __restrict__ xw1, const float* __restrict__ xb1,
    const float* __restrict__ xw2, const float* __restrict__ xb2,
    const float* __restrict__ cw1, const float* __restrict__ cb1,
    const float* __restrict__ cw2, const float* __restrict__ cb2,
    const float* __restrict__ cw3, const float* __restrict__ cb3,
    float* __restrict__ efg, float* __restrict__ accg) {
    __shared__ float xs[32 * 288];  // reused as 3 x [32][96] slots after layer 1
    __shared__ float wbuf[32 * HID];
    __shared__ float t1[32 * 96];
    __shared__ float bcb[32 * 4];
    __shared__ float trs[32 * 4];
    const int t = threadIdx.x;
    const int e0 = blockIdx.x * 32;
    const int n0 = blockIdx.x * 8;

    for (int idx = t; idx < 32 * 288; idx += 256) {
        int r = idx / 288, k = idx % 288;
        int e = e0 + r;
        float v;
        if (k < 96)       v = hng[(size_t)(e >> 2) * 96 + k];
        else if (k < 192) v = hng[(size_t)eic[e] * 96 + (k - 96)];
        else              v = ea[(size_t)e * 96 + (k - 192)];
        xs[idx] = v;
    }
    float acc[4][3];
    mlp_tile<4>(xw1, 288, wbuf, [&](int r, int k) { return xs[r * 288 + k]; }, t, acc);
    {
        const int tx = t & 31, ty = t >> 5, c0 = tx * 3;
#pragma unroll
        for (int i = 0; i < 4; i++)
#pragma unroll
            for (int j = 0; j < 3; j++)
                t1[(ty * 4 + i) * 96 + c0 + j] = sp_f(acc[i][j] + xb1[c0 + j]);
    }
    mlp_tile<4>(xw2, 96, wbuf, [&](int r, int k) { return t1[r * 96 + k]; }, t, acc);
    float* A0 = xs;
    float* A1 = xs + 32 * 96;
    float* A2 = xs + 64 * 96;
    {
        const int tx = t & 31, ty = t >> 5, c0 = tx * 3;
#pragma unroll
        for (int i = 0; i < 4; i++)
#pragma unroll
            for (int j = 0; j < 3; j++) {
                int r = ty * 4 + i, c = c0 + j;
                float v = acc[i][j] + xb2[c] + efg[(size_t)(e0 + r) * 96 + c];
                efg[(size_t)(e0 + r) * 96 + c] = v;  // ef2 output (in place)
                A0[r * 96 + c] = v;
            }
    }
    mlp_tile<4>(cw1, 96, wbuf, [&](int r, int k) { return A0[r * 96 + k]; }, t, acc);
    {
        const int tx = t & 31, ty = t >> 5, c0 = tx * 3;
#pragma unroll
        for (int i = 0; i < 4; i++)
#pragma unroll
            for (int j = 0; j < 3; j++)
                A1[(ty * 4 + i) * 96 + c0 + j] = sp_f(acc[i][j] + cb1[c0 + j]);
    }
    mlp_tile<4>(cw2, 96, wbuf, [&](int r, int k) { return A1[r * 96 + k]; }, t, acc);
    {
        const int tx = t & 31, ty = t >> 5, c0 = tx * 3;
#pragma unroll
        for (int i = 0; i < 4; i++)
#pragma unroll
            for (int j = 0; j < 3; j++)
                A2[(ty * 4 + i) * 96 + c0 + j] = sp_f(acc[i][j] + cb2[c0 + j]);
    }
    __syncthreads();
    // bc = t @ cw3 + cb3 : one thread per (edge, 3-comp)
    if (t < 96) {
        int r = t / 3, j = t % 3;
        float s = cb3[j];
        for (int k = 0; k < 96; k++) s = fmaf(A2[r * 96 + k], cw3[k * 3 + j], s);
        bcb[r * 4 + j] = s;
    }
    __syncthreads();
    // geometry per edge
    if (t < 32) {
        int e = e0 + t;
        int rn = e >> 2, cn = eic[e];
        float r0 = cp[(size_t)rn * 3 + 0], r1 = cp[(size_t)rn * 3 + 1], r2 = cp[(size_t)rn * 3 + 2];
        float q0 = cp[(size_t)cn * 3 + 0], q1 = cp[(size_t)cn * 3 + 1], q2 = cp[(size_t)cn * 3 + 2];
        float d0 = r0 - q0, d1 = r1 - q1, d2 = r2 - q2;
        float x0 = r1 * q2 - r2 * q1;       // cc = cross(coord_pre[row], coord_pre[col])
        float x1 = r2 * q0 - r0 * q2;
        float x2 = r0 * q1 - r1 * q0;
        float v0 = d1 * x2 - d2 * x1;       // cv = cross(cd, cc)
        float v1 = d2 * x0 - d0 * x2;
        float v2 = d0 * x1 - d1 * x0;
        float b0 = bcb[t * 4 + 0], b1 = bcb[t * 4 + 1], b2 = bcb[t * 4 + 2];
        trs[t * 4 + 0] = fminf(fmaxf(d0 * b0 + x0 * b1 + v0 * b2, -100.f), 100.f);
        trs[t * 4 + 1] = fminf(fmaxf(d1 * b0 + x1 * b1 + v1 * b2, -100.f), 100.f);
        trs[t * 4 + 2] = fminf(fmaxf(d2 * b0 + x2 * b1 + v2 * b2, -100.f), 100.f);
    }
    __syncthreads();
    // acc = mean over each node's 4 edges
    if (t < 24) {
        int nd = t / 3, j = t % 3;
        float s = (trs[(nd * 4 + 0) * 4 + j] + trs[(nd * 4 + 1) * 4 + j] +
                   trs[(nd * 4 + 2) * 4 + j] + trs[(nd * 4 + 3) * 4 + j]) * 0.25f;
        accg[(size_t)(n0 + nd) * 3 + j] = s;
    }
}

extern "C" void kernel_launch(void* const* d_in, const int* in_sizes, int n_in,
                              void* d_out, int out_size, void* d_ws, size_t ws_size,
                              hipStream_t stream) {
    const float* h   = (const float*)d_in[0];
    const int*   ei  = (const int*)d_in[1];
    const float* cp  = (const float*)d_in[3];   // coord_pre
    const float* ea  = (const float*)d_in[5];   // edge_attr
    const float* ew1 = (const float*)d_in[6];
    const float* eb1 = (const float*)d_in[7];
    const float* ew2 = (const float*)d_in[8];
    const float* eb2 = (const float*)d_in[9];
    const float* xw1 = (const float*)d_in[10];
    const float* xb1 = (const float*)d_in[11];
    const float* xw2 = (const float*)d_in[12];
    const float* xb2 = (const float*)d_in[13];
    const float* nw1 = (const float*)d_in[14];
    const float* nb1 = (const float*)d_in[15];
    const float* nw2 = (const float*)d_in[16];
    const float* nb2 = (const float*)d_in[17];
    const float* cw1 = (const float*)d_in[18];
    const float* cb1 = (const float*)d_in[19];
    const float* cw2 = (const float*)d_in[20];
    const float* cb2 = (const float*)d_in[21];
    const float* cw3 = (const float*)d_in[22];
    const float* cb3 = (const float*)d_in[23];
    const float* qw  = (const float*)d_in[24];
    const float* qb  = (const float*)d_in[25];
    const float* kw  = (const float*)d_in[26];
    const float* kb  = (const float*)d_in[27];
    const float* vw  = (const float*)d_in[28];
    const float* vb  = (const float*)d_in[29];
    const float* g1  = (const float*)d_in[30];
    const float* be1 = (const float*)d_in[31];
    const float* g2  = (const float*)d_in[32];
    const float* be2 = (const float*)d_in[33];

    float* out  = (float*)d_out;
    float* accg = out;                                   // [NN,3]
    float* hng  = out + (size_t)NN * 3;                  // [NN,96]
    float* efg  = out + (size_t)NN * 3 + (size_t)NN * 96; // [NE,96] (ef then ef2)
    const int* eic = ei + NE;                            // col indices

    k_edge_mlp<<<NE / 32, 256, 0, stream>>>(h, eic, ea, ew1, eb1, ew2, eb2, efg);
    k_attn_node<<<NN / 8, 256, 0, stream>>>(h, efg, qw, qb, kw, kb, vw, vb, nw1,
                                            nb1, nw2, nb2, g1, be1, g2, be2, hng);
    k_enhance_coord<<<NE / 32, 256, 0, stream>>>(hng, eic, ea, cp, xw1, xb1, xw2,
                                                 xb2, cw1, cb1, cw2, cb2, cw3, cb3,
                                                 efg, accg);
}

// Round 2
// 921.345 us; speedup vs baseline: 4.8623x; 4.8623x over previous
//
#include <hip/hip_runtime.h>

#define HID 96
#define B_GRAPHS 16384
#define NN (B_GRAPHS * 5)          // 81920 nodes
#define NE (NN * 4)                // 327680 edges

typedef __attribute__((ext_vector_type(8))) short bf8;   // 8 x bf16 (4 VGPR)
typedef __attribute__((ext_vector_type(4))) short s4;    // 4 x bf16 (8B)
typedef __attribute__((ext_vector_type(4))) float f4;    // MFMA accumulator

// d_ws layout (bf16 elements) — all weights transposed to [N=96][K]
#define OFF_EW1 0
#define OFF_EW2 27648
#define OFF_KW  36864
#define OFF_VW  55296
#define OFF_QW  64512
#define OFF_NW1 73728
#define OFF_NW2 92160
#define OFF_XW1 101376
#define OFF_XW2 129024
#define OFF_CW1 138240
#define OFF_CW2 147456
#define WS_ELEMS 156672

__device__ __forceinline__ float sp_f(float x) {
    return fmaxf(x, 0.0f) + log1pf(expf(-fabsf(x)));
}
__device__ __forceinline__ short tobf(float x) {
    union { float f; unsigned u; } v; v.f = x;
    unsigned r = v.u + 0x7fff + ((v.u >> 16) & 1);   // RNE
    return (short)(r >> 16);
}
__device__ __forceinline__ float frombf(short s) {
    union { float f; unsigned u; } v;
    v.u = ((unsigned)(unsigned short)s) << 16;
    return v.f;
}

// out[row][col] += sum_k a(row,k) * W[k][col] for a 16-row stripe, NT n-tiles.
// wT is bf16 [96][K] (transposed). A-frag: row=lane&15, k=k0+(lane>>4)*8+j.
template <int K, int NT, class AF>
__device__ __forceinline__ void gemmNT(const short* __restrict__ wT, int nb,
                                       AF aload, f4* acc) {
#pragma unroll
    for (int i = 0; i < NT; i++)
#pragma unroll
        for (int j = 0; j < 4; j++) acc[i][j] = 0.0f;
    const int lane = threadIdx.x & 63;
    const int kg = lane >> 4, ln = lane & 15;
#pragma unroll
    for (int k0 = 0; k0 < K; k0 += 32) {
        bf8 a = aload(ln, k0, kg);
#pragma unroll
        for (int i = 0; i < NT; i++) {
            int col = (nb + i) * 16 + ln;
            bf8 b = *(const bf8*)(wT + (size_t)col * K + k0 + kg * 8);
            acc[i] = __builtin_amdgcn_mfma_f32_16x16x32_bf16(a, b, acc[i], 0, 0, 0);
        }
    }
}

// ---------------- Prep: transpose+convert weights into d_ws ------------------
__global__ __launch_bounds__(256) void k_prep(
    const float* ew1, const float* ew2, const float* kw, const float* vw,
    const float* qw, const float* nw1, const float* nw2, const float* xw1,
    const float* xw2, const float* cw1, const float* cw2, short* wsT) {
    const float* srcs[11] = {ew1, ew2, kw, vw, qw, nw1, nw2, xw1, xw2, cw1, cw2};
    const int Ks[11] = {288, 96, 192, 96, 96, 192, 96, 288, 96, 96, 96};
    const int offs[11] = {OFF_EW1, OFF_EW2, OFF_KW, OFF_VW, OFF_QW, OFF_NW1,
                          OFF_NW2, OFF_XW1, OFF_XW2, OFF_CW1, OFF_CW2};
    int b = blockIdx.x;
    const float* src = srcs[b];
    int K = Ks[b], off = offs[b];
    for (int idx = threadIdx.x; idx < K * 96; idx += 256) {
        int n = idx / K, k = idx - n * K;
        wsT[off + idx] = tobf(src[(size_t)k * 96 + n]);
    }
}

// ---------------- Kernel 1: edge_mlp -> ef (f32, into d_out ef2 region) ------
__global__ __launch_bounds__(256, 3) void k1_edge(
    const float* __restrict__ h, const int* __restrict__ eic,
    const float* __restrict__ ea, const short* __restrict__ wsT,
    const float* __restrict__ eb1, const float* __restrict__ eb2,
    float* __restrict__ efg) {
    __shared__ short xs[64 * 288];
    __shared__ short t1[64 * 96];
    const int t = threadIdx.x;
    const int e0 = blockIdx.x * 64;

    for (int idx = t; idx < 64 * 72; idx += 256) {
        int r = idx / 72, c = (idx - r * 72) * 4;
        int e = e0 + r;
        const float* src;
        if (c < 96)       src = &h[(size_t)(e >> 2) * 96 + c];
        else if (c < 192) src = &h[(size_t)eic[e] * 96 + (c - 96)];
        else              src = &ea[(size_t)e * 96 + (c - 192)];
        f4 v = *(const f4*)src;
        s4 b; b[0] = tobf(v[0]); b[1] = tobf(v[1]); b[2] = tobf(v[2]); b[3] = tobf(v[3]);
        *(s4*)&xs[(r * 288 + c) ^ ((r & 7) << 3)] = b;
    }
    __syncthreads();
    const int lane = t & 63, w = t >> 6;
    const int kg = lane >> 4, ln = lane & 15;
    const int r0 = w * 16;
    f4 acc[6];
    gemmNT<288, 6>(wsT + OFF_EW1, 0,
        [&](int ln_, int k0, int kg_) {
            int row = r0 + ln_;
            return *(const bf8*)&xs[(row * 288 + k0 + kg_ * 8) ^ ((row & 7) << 3)];
        }, acc);
#pragma unroll
    for (int nt = 0; nt < 6; nt++) {
        int col = nt * 16 + ln;
        float bia = eb1[col];
#pragma unroll
        for (int j = 0; j < 4; j++) {
            int row = r0 + kg * 4 + j;
            t1[(row * 96 + col) ^ ((row & 7) << 3)] = tobf(sp_f(acc[nt][j] + bia));
        }
    }
    __syncthreads();
    gemmNT<96, 6>(wsT + OFF_EW2, 0,
        [&](int ln_, int k0, int kg_) {
            int row = r0 + ln_;
            return *(const bf8*)&t1[(row * 96 + k0 + kg_ * 8) ^ ((row & 7) << 3)];
        }, acc);
#pragma unroll
    for (int nt = 0; nt < 6; nt++) {
        int col = nt * 16 + ln;
        float bia = eb2[col];
#pragma unroll
        for (int j = 0; j < 4; j++) {
            int row = r0 + kg * 4 + j;
            efg[(size_t)(e0 + row) * 96 + col] = sp_f(acc[nt][j] + bia);
        }
    }
}

// ---------------- Kernel 2: attention + node model -> hn ---------------------
__global__ __launch_bounds__(256, 3) void k2_attn(
    const float* __restrict__ h, const float* __restrict__ efg,
    const short* __restrict__ wsT,
    const float* __restrict__ qb, const float* __restrict__ kb,
    const float* __restrict__ vb,
    const float* __restrict__ nb1, const float* __restrict__ nb2,
    const float* __restrict__ g1, const float* __restrict__ be1,
    const float* __restrict__ g2, const float* __restrict__ be2,
    float* __restrict__ hng) {
    __shared__ short hsb[16 * 96];
    __shared__ short efs[64 * 96];
    __shared__ short qhb[16 * 96];
    __shared__ short kvb[64 * 96];   // kh, then vh
    __shared__ short agb[16 * 96];
    __shared__ short t1b[16 * 96];
    __shared__ float outb[16 * 96];
    __shared__ float sc[64 * 3];
    const int t = threadIdx.x;
    const int n0 = blockIdx.x * 16;
    const int e0 = n0 * 4;

    for (int idx = t; idx < 16 * 24; idx += 256) {
        int r = idx / 24, c = (idx - r * 24) * 4;
        f4 v = *(const f4*)&h[(size_t)(n0 + r) * 96 + c];
        s4 b; b[0] = tobf(v[0]); b[1] = tobf(v[1]); b[2] = tobf(v[2]); b[3] = tobf(v[3]);
        *(s4*)&hsb[(r * 96 + c) ^ ((r & 7) << 3)] = b;
    }
    for (int idx = t; idx < 64 * 24; idx += 256) {
        int r = idx / 24, c = (idx - r * 24) * 4;
        f4 v = *(const f4*)&efg[(size_t)(e0 + r) * 96 + c];
        s4 b; b[0] = tobf(v[0]); b[1] = tobf(v[1]); b[2] = tobf(v[2]); b[3] = tobf(v[3]);
        *(s4*)&efs[(r * 96 + c) ^ ((r & 7) << 3)] = b;
    }
    __syncthreads();
    const int lane = t & 63, w = t >> 6;
    const int kg = lane >> 4, ln = lane & 15;
    const int r0 = w * 16;
    // q projection: waves 0..2 own 2 n-tiles each (M = 16 nodes)
    if (w < 3) {
        f4 qa[2];
        gemmNT<96, 2>(wsT + OFF_QW, 2 * w,
            [&](int ln_, int k0, int kg_) {
                return *(const bf8*)&hsb[(ln_ * 96 + k0 + kg_ * 8) ^ ((ln_ & 7) << 3)];
            }, qa);
#pragma unroll
        for (int i = 0; i < 2; i++) {
            int col = (2 * w + i) * 16 + ln;
            float bia = qb[col];
#pragma unroll
            for (int j = 0; j < 4; j++) {
                int row = kg * 4 + j;
                qhb[(row * 96 + col) ^ ((row & 7) << 3)] = tobf(qa[i][j] + bia);
            }
        }
    }
    // kh: all waves, 16 edges each; input = concat[h[row], ef]
    {
        f4 acc[6];
        gemmNT<192, 6>(wsT + OFF_KW, 0,
            [&](int ln_, int k0, int kg_) {
                int e = r0 + ln_;
                if (k0 < 96) {
                    int row = e >> 2;
                    return *(const bf8*)&hsb[(row * 96 + k0 + kg_ * 8) ^ ((row & 7) << 3)];
                } else {
                    return *(const bf8*)&efs[(e * 96 + (k0 - 96) + kg_ * 8) ^ ((e & 7) << 3)];
                }
            }, acc);
#pragma unroll
        for (int nt = 0; nt < 6; nt++) {
            int col = nt * 16 + ln;
            float bia = kb[col];
#pragma unroll
            for (int j = 0; j < 4; j++) {
                int row = r0 + kg * 4 + j;
                kvb[(row * 96 + col) ^ ((row & 7) << 3)] = tobf(acc[nt][j] + bia);
            }
        }
    }
    __syncthreads();
    // scores: one thread per (edge, head), dot over d=32
    if (t < 192) {
        int e = t / 3, hd = t - e * 3;
        int nd = e >> 2;
        float s = 0.f;
#pragma unroll
        for (int c8 = 0; c8 < 4; c8++) {
            int c = hd * 32 + c8 * 8;
            bf8 qv = *(const bf8*)&qhb[(nd * 96 + c) ^ ((nd & 7) << 3)];
            bf8 kv = *(const bf8*)&kvb[(e * 96 + c) ^ ((e & 7) << 3)];
#pragma unroll
            for (int j = 0; j < 8; j++) s = fmaf(frombf(qv[j]), frombf(kv[j]), s);
        }
        sc[e * 3 + hd] = s * 0.17677669529663687f;   // 1/sqrt(32)
    }
    __syncthreads();
    // softmax over 4 edges per (node, head)
    if (t < 48) {
        int nd = t / 3, hd = t - nd * 3;
        float v0 = sc[(nd * 4 + 0) * 3 + hd], v1 = sc[(nd * 4 + 1) * 3 + hd];
        float v2 = sc[(nd * 4 + 2) * 3 + hd], v3 = sc[(nd * 4 + 3) * 3 + hd];
        float m = fmaxf(fmaxf(v0, v1), fmaxf(v2, v3));
        float p0 = expf(v0 - m), p1 = expf(v1 - m), p2 = expf(v2 - m), p3 = expf(v3 - m);
        float inv = 1.f / (p0 + p1 + p2 + p3);
        sc[(nd * 4 + 0) * 3 + hd] = p0 * inv;
        sc[(nd * 4 + 1) * 3 + hd] = p1 * inv;
        sc[(nd * 4 + 2) * 3 + hd] = p2 * inv;
        sc[(nd * 4 + 3) * 3 + hd] = p3 * inv;
    }
    // vh: all waves (overwrites kvb; its readers done at the barrier above)
    {
        f4 acc[6];
        gemmNT<96, 6>(wsT + OFF_VW, 0,
            [&](int ln_, int k0, int kg_) {
                int e = r0 + ln_;
                return *(const bf8*)&efs[(e * 96 + k0 + kg_ * 8) ^ ((e & 7) << 3)];
            }, acc);
#pragma unroll
        for (int nt = 0; nt < 6; nt++) {
            int col = nt * 16 + ln;
            float bia = vb[col];
#pragma unroll
            for (int j = 0; j < 4; j++) {
                int row = r0 + kg * 4 + j;
                kvb[(row * 96 + col) ^ ((row & 7) << 3)] = tobf(acc[nt][j] + bia);
            }
        }
    }
    __syncthreads();
    // agg = sum_e attw * vh, LayerNorm(g1, be1) -> agb (bf16)
    {
        const int tx = t & 31, ty = t >> 5, c0 = tx * 3;
        for (int nd = ty; nd < 16; nd += 8) {
            float av[3];
#pragma unroll
            for (int j = 0; j < 3; j++) {
                int c = c0 + j, hd = c >> 5;
                float s = 0.f;
#pragma unroll
                for (int k = 0; k < 4; k++) {
                    int e = nd * 4 + k;
                    s = fmaf(sc[e * 3 + hd],
                             frombf(kvb[(e * 96 + c) ^ ((e & 7) << 3)]), s);
                }
                av[j] = s;
            }
            float ps = av[0] + av[1] + av[2];
            float ps2 = av[0] * av[0] + av[1] * av[1] + av[2] * av[2];
            for (int m = 1; m < 32; m <<= 1) {
                ps += __shfl_xor(ps, m);
                ps2 += __shfl_xor(ps2, m);
            }
            float mu = ps * (1.f / 96.f);
            float var = ps2 * (1.f / 96.f) - mu * mu;
            float rs = rsqrtf(var + 1e-5f);
#pragma unroll
            for (int j = 0; j < 3; j++) {
                int c = c0 + j;
                agb[(nd * 96 + c) ^ ((nd & 7) << 3)] =
                    tobf((av[j] - mu) * rs * g1[c] + be1[c]);
            }
        }
    }
    __syncthreads();
    // node MLP layer 1 (M=16, K=192): waves 0..2
    if (w < 3) {
        f4 a2[2];
        gemmNT<192, 2>(wsT + OFF_NW1, 2 * w,
            [&](int ln_, int k0, int kg_) {
                if (k0 < 96)
                    return *(const bf8*)&hsb[(ln_ * 96 + k0 + kg_ * 8) ^ ((ln_ & 7) << 3)];
                else
                    return *(const bf8*)&agb[(ln_ * 96 + (k0 - 96) + kg_ * 8) ^ ((ln_ & 7) << 3)];
            }, a2);
#pragma unroll
        for (int i = 0; i < 2; i++) {
            int col = (2 * w + i) * 16 + ln;
            float bia = nb1[col];
#pragma unroll
            for (int j = 0; j < 4; j++) {
                int row = kg * 4 + j;
                t1b[(row * 96 + col) ^ ((row & 7) << 3)] = tobf(sp_f(a2[i][j] + bia));
            }
        }
    }
    __syncthreads();
    // node MLP layer 2 + residual
    if (w < 3) {
        f4 a2[2];
        gemmNT<96, 2>(wsT + OFF_NW2, 2 * w,
            [&](int ln_, int k0, int kg_) {
                return *(const bf8*)&t1b[(ln_ * 96 + k0 + kg_ * 8) ^ ((ln_ & 7) << 3)];
            }, a2);
#pragma unroll
        for (int i = 0; i < 2; i++) {
            int col = (2 * w + i) * 16 + ln;
            float bia = nb2[col];
#pragma unroll
            for (int j = 0; j < 4; j++) {
                int row = kg * 4 + j;
                outb[row * 96 + col] = a2[i][j] + bia + h[(size_t)(n0 + row) * 96 + col];
            }
        }
    }
    __syncthreads();
    // LN2 -> hng
    {
        const int tx = t & 31, ty = t >> 5, c0 = tx * 3;
        for (int nd = ty; nd < 16; nd += 8) {
            float xv[3] = {outb[nd * 96 + c0], outb[nd * 96 + c0 + 1], outb[nd * 96 + c0 + 2]};
            float ps = xv[0] + xv[1] + xv[2];
            float ps2 = xv[0] * xv[0] + xv[1] * xv[1] + xv[2] * xv[2];
            for (int m = 1; m < 32; m <<= 1) {
                ps += __shfl_xor(ps, m);
                ps2 += __shfl_xor(ps2, m);
            }
            float mu = ps * (1.f / 96.f);
            float var = ps2 * (1.f / 96.f) - mu * mu;
            float rs = rsqrtf(var + 1e-5f);
#pragma unroll
            for (int j = 0; j < 3; j++) {
                int c = c0 + j;
                hng[(size_t)(n0 + nd) * 96 + c] = (xv[j] - mu) * rs * g2[c] + be2[c];
            }
        }
    }
}

// ---------------- Kernel 3: enhance (ef2) + coord MLP + acc ------------------
__global__ __launch_bounds__(256, 3) void k3_coord(
    const float* __restrict__ hng, const int* __restrict__ eic,
    const float* __restrict__ ea, const float* __restrict__ cp,
    const short* __restrict__ wsT,
    const float* __restrict__ xb1, const float* __restrict__ xb2,
    const float* __restrict__ cb1, const float* __restrict__ cb2,
    const float* __restrict__ cw3, const float* __restrict__ cb3,
    float* __restrict__ efg, float* __restrict__ accg) {
    __shared__ short xs[64 * 288];   // reused: A0=xs, A1=xs+6144, A2=xs+12288
    __shared__ short t1[64 * 96];
    __shared__ float cw3s[96 * 3];
    __shared__ float bcb[64 * 3];
    __shared__ float trs[64 * 4];
    const int t = threadIdx.x;
    const int e0 = blockIdx.x * 64;
    const int n0 = blockIdx.x * 16;

    for (int idx = t; idx < 64 * 72; idx += 256) {
        int r = idx / 72, c = (idx - r * 72) * 4;
        int e = e0 + r;
        const float* src;
        if (c < 96)       src = &hng[(size_t)(e >> 2) * 96 + c];
        else if (c < 192) src = &hng[(size_t)eic[e] * 96 + (c - 96)];
        else              src = &ea[(size_t)e * 96 + (c - 192)];
        f4 v = *(const f4*)src;
        s4 b; b[0] = tobf(v[0]); b[1] = tobf(v[1]); b[2] = tobf(v[2]); b[3] = tobf(v[3]);
        *(s4*)&xs[(r * 288 + c) ^ ((r & 7) << 3)] = b;
    }
    for (int idx = t; idx < 96 * 3; idx += 256) cw3s[idx] = cw3[idx];
    __syncthreads();
    const int lane = t & 63, w = t >> 6;
    const int kg = lane >> 4, ln = lane & 15;
    const int r0 = w * 16;
    f4 acc[6];
    // enhance layer 1 (K=288)
    gemmNT<288, 6>(wsT + OFF_XW1, 0,
        [&](int ln_, int k0, int kg_) {
            int row = r0 + ln_;
            return *(const bf8*)&xs[(row * 288 + k0 + kg_ * 8) ^ ((row & 7) << 3)];
        }, acc);
#pragma unroll
    for (int nt = 0; nt < 6; nt++) {
        int col = nt * 16 + ln;
        float bia = xb1[col];
#pragma unroll
        for (int j = 0; j < 4; j++) {
            int row = r0 + kg * 4 + j;
            t1[(row * 96 + col) ^ ((row & 7) << 3)] = tobf(sp_f(acc[nt][j] + bia));
        }
    }
    __syncthreads();
    // enhance layer 2 + residual ef -> ef2 (global) and A0 (bf16)
    short* A0 = xs;
    short* A1 = xs + 6144;
    short* A2 = xs + 12288;
    gemmNT<96, 6>(wsT + OFF_XW2, 0,
        [&](int ln_, int k0, int kg_) {
            int row = r0 + ln_;
            return *(const bf8*)&t1[(row * 96 + k0 + kg_ * 8) ^ ((row & 7) << 3)];
        }, acc);
#pragma unroll
    for (int nt = 0; nt < 6; nt++) {
        int col = nt * 16 + ln;
        float bia = xb2[col];
#pragma unroll
        for (int j = 0; j < 4; j++) {
            int row = r0 + kg * 4 + j;
            size_t gi = (size_t)(e0 + row) * 96 + col;
            float v = acc[nt][j] + bia + efg[gi];
            efg[gi] = v;
            A0[(row * 96 + col) ^ ((row & 7) << 3)] = tobf(v);
        }
    }
    __syncthreads();
    // coord MLP layer 1
    gemmNT<96, 6>(wsT + OFF_CW1, 0,
        [&](int ln_, int k0, int kg_) {
            int row = r0 + ln_;
            return *(const bf8*)&A0[(row * 96 + k0 + kg_ * 8) ^ ((row & 7) << 3)];
        }, acc);
#pragma unroll
    for (int nt = 0; nt < 6; nt++) {
        int col = nt * 16 + ln;
        float bia = cb1[col];
#pragma unroll
        for (int j = 0; j < 4; j++) {
            int row = r0 + kg * 4 + j;
            A1[(row * 96 + col) ^ ((row & 7) << 3)] = tobf(sp_f(acc[nt][j] + bia));
        }
    }
    __syncthreads();
    // coord MLP layer 2
    gemmNT<96, 6>(wsT + OFF_CW2, 0,
        [&](int ln_, int k0, int kg_) {
            int row = r0 + ln_;
            return *(const bf8*)&A1[(row * 96 + k0 + kg_ * 8) ^ ((row & 7) << 3)];
        }, acc);
#pragma unroll
    for (int nt = 0; nt < 6; nt++) {
        int col = nt * 16 + ln;
        float bia = cb2[col];
#pragma unroll
        for (int j = 0; j < 4; j++) {
            int row = r0 + kg * 4 + j;
            A2[(row * 96 + col) ^ ((row & 7) << 3)] = tobf(sp_f(acc[nt][j] + bia));
        }
    }
    __syncthreads();
    // bc = A2 @ cw3 + cb3 : one thread per (edge, component)
    if (t < 192) {
        int e = t / 3, j = t - e * 3;
        float s = cb3[j];
#pragma unroll
        for (int c8 = 0; c8 < 12; c8++) {
            bf8 av = *(const bf8*)&A2[(e * 96 + c8 * 8) ^ ((e & 7) << 3)];
#pragma unroll
            for (int jj = 0; jj < 8; jj++)
                s = fmaf(frombf(av[jj]), cw3s[(c8 * 8 + jj) * 3 + j], s);
        }
        bcb[e * 3 + j] = s;
    }
    __syncthreads();
    // geometry per edge
    if (t < 64) {
        int e = e0 + t;
        int rn = e >> 2, cn = eic[e];
        float r0c = cp[(size_t)rn * 3 + 0], r1c = cp[(size_t)rn * 3 + 1], r2c = cp[(size_t)rn * 3 + 2];
        float q0 = cp[(size_t)cn * 3 + 0], q1 = cp[(size_t)cn * 3 + 1], q2 = cp[(size_t)cn * 3 + 2];
        float d0 = r0c - q0, d1 = r1c - q1, d2 = r2c - q2;
        float x0 = r1c * q2 - r2c * q1;
        float x1 = r2c * q0 - r0c * q2;
        float x2 = r0c * q1 - r1c * q0;
        float v0 = d1 * x2 - d2 * x1;
        float v1 = d2 * x0 - d0 * x2;
        float v2 = d0 * x1 - d1 * x0;
        float b0 = bcb[t * 3 + 0], b1 = bcb[t * 3 + 1], b2 = bcb[t * 3 + 2];
        trs[t * 4 + 0] = fminf(fmaxf(d0 * b0 + x0 * b1 + v0 * b2, -100.f), 100.f);
        trs[t * 4 + 1] = fminf(fmaxf(d1 * b0 + x1 * b1 + v1 * b2, -100.f), 100.f);
        trs[t * 4 + 2] = fminf(fmaxf(d2 * b0 + x2 * b1 + v2 * b2, -100.f), 100.f);
    }
    __syncthreads();
    if (t < 48) {
        int nd = t / 3, j = t - nd * 3;
        float s = (trs[(nd * 4 + 0) * 4 + j] + trs[(nd * 4 + 1) * 4 + j] +
                   trs[(nd * 4 + 2) * 4 + j] + trs[(nd * 4 + 3) * 4 + j]) * 0.25f;
        accg[(size_t)(n0 + nd) * 3 + j] = s;
    }
}

extern "C" void kernel_launch(void* const* d_in, const int* in_sizes, int n_in,
                              void* d_out, int out_size, void* d_ws, size_t ws_size,
                              hipStream_t stream) {
    const float* h   = (const float*)d_in[0];
    const int*   ei  = (const int*)d_in[1];
    const float* cp  = (const float*)d_in[3];
    const float* ea  = (const float*)d_in[5];
    const float* ew1 = (const float*)d_in[6];
    const float* eb1 = (const float*)d_in[7];
    const float* ew2 = (const float*)d_in[8];
    const float* eb2 = (const float*)d_in[9];
    const float* xw1 = (const float*)d_in[10];
    const float* xb1 = (const float*)d_in[11];
    const float* xw2 = (const float*)d_in[12];
    const float* xb2 = (const float*)d_in[13];
    const float* nw1 = (const float*)d_in[14];
    const float* nb1 = (const float*)d_in[15];
    const float* nw2 = (const float*)d_in[16];
    const float* nb2 = (const float*)d_in[17];
    const float* cw1 = (const float*)d_in[18];
    const float* cb1 = (const float*)d_in[19];
    const float* cw2 = (const float*)d_in[20];
    const float* cb2 = (const float*)d_in[21];
    const float* cw3 = (const float*)d_in[22];
    const float* cb3 = (const float*)d_in[23];
    const float* qw  = (const float*)d_in[24];
    const float* qb  = (const float*)d_in[25];
    const float* kw  = (const float*)d_in[26];
    const float* kb  = (const float*)d_in[27];
    const float* vw  = (const float*)d_in[28];
    const float* vb  = (const float*)d_in[29];
    const float* g1  = (const float*)d_in[30];
    const float* be1 = (const float*)d_in[31];
    const float* g2  = (const float*)d_in[32];
    const float* be2 = (const float*)d_in[33];

    float* out  = (float*)d_out;
    float* accg = out;                                    // [NN,3]
    float* hng  = out + (size_t)NN * 3;                   // [NN,96]
    float* efg  = out + (size_t)NN * 3 + (size_t)NN * 96; // [NE,96] ef then ef2
    const int* eic = ei + NE;
    short* wsT = (short*)d_ws;                            // 313 KB of weights

    k_prep<<<11, 256, 0, stream>>>(ew1, ew2, kw, vw, qw, nw1, nw2, xw1, xw2,
                                   cw1, cw2, wsT);
    k1_edge<<<NE / 64, 256, 0, stream>>>(h, eic, ea, wsT, eb1, eb2, efg);
    k2_attn<<<NN / 16, 256, 0, stream>>>(h, efg, wsT, qb, kb, vb, nb1, nb2,
                                         g1, be1, g2, be2, hng);
    k3_coord<<<NE / 64, 256, 0, stream>>>(hng, eic, ea, cp, wsT, xb1, xb2,
                                          cb1, cb2, cw3, cb3, efg, accg);
}

// Round 3
// 702.252 us; speedup vs baseline: 6.3793x; 1.3120x over previous
//
#include <hip/hip_runtime.h>
#include <hip/hip_bf16.h>

#define HID 96
#define B_GRAPHS 16384
#define NN (B_GRAPHS * 5)          // 81920 nodes
#define NE (NN * 4)                // 327680 edges

typedef __attribute__((ext_vector_type(8))) short bf8;   // 8 x bf16 (4 VGPR)
typedef __attribute__((ext_vector_type(4))) short s4;    // 4 x bf16 (8B)
typedef __attribute__((ext_vector_type(4))) float f4;    // MFMA accumulator

// d_ws layout (bf16 elements) — all weights transposed to [N=96][K]
#define OFF_EW1 0
#define OFF_EW2 27648
#define OFF_KW  36864
#define OFF_VW  55296
#define OFF_QW  64512
#define OFF_NW1 73728
#define OFF_NW2 92160
#define OFF_XW1 101376
#define OFF_XW2 129024
#define OFF_CW1 138240
#define OFF_CW2 147456
#define WS_ELEMS 156672

// fast softplus: max(x,0) + log(1+exp(-|x|)) via v_exp_f32/v_log_f32
__device__ __forceinline__ float sp_f(float x) {
    return fmaxf(x, 0.0f) + __logf(1.0f + __expf(-fabsf(x)));
}
__device__ __forceinline__ short tobf(float x) {
    return __builtin_bit_cast(short, __float2bfloat16(x));
}
__device__ __forceinline__ float frombf(short s) {
    union { float f; unsigned u; } v;
    v.u = ((unsigned)(unsigned short)s) << 16;
    return v.f;
}

// out[row][col] += sum_k a(row,k) * W[k][col] for a 16-row stripe, NT n-tiles.
// wT is bf16 [96][K] (transposed). A-frag: row=lane&15, k=k0+(lane>>4)*8+j.
template <int K, int NT, class AF>
__device__ __forceinline__ void gemmNT(const short* __restrict__ wT, int nb,
                                       AF aload, f4* acc) {
#pragma unroll
    for (int i = 0; i < NT; i++)
#pragma unroll
        for (int j = 0; j < 4; j++) acc[i][j] = 0.0f;
    const int lane = threadIdx.x & 63;
    const int kg = lane >> 4, ln = lane & 15;
#pragma unroll
    for (int k0 = 0; k0 < K; k0 += 32) {
        bf8 a = aload(ln, k0, kg);
#pragma unroll
        for (int i = 0; i < NT; i++) {
            int col = (nb + i) * 16 + ln;
            bf8 b = *(const bf8*)(wT + (size_t)col * K + k0 + kg * 8);
            acc[i] = __builtin_amdgcn_mfma_f32_16x16x32_bf16(a, b, acc[i], 0, 0, 0);
        }
    }
}

// ---------------- Prep: transpose+convert weights into d_ws ------------------
__global__ __launch_bounds__(256) void k_prep(
    const float* ew1, const float* ew2, const float* kw, const float* vw,
    const float* qw, const float* nw1, const float* nw2, const float* xw1,
    const float* xw2, const float* cw1, const float* cw2, short* wsT) {
    const float* srcs[11] = {ew1, ew2, kw, vw, qw, nw1, nw2, xw1, xw2, cw1, cw2};
    const int Ks[11] = {288, 96, 192, 96, 96, 192, 96, 288, 96, 96, 96};
    const int offs[11] = {OFF_EW1, OFF_EW2, OFF_KW, OFF_VW, OFF_QW, OFF_NW1,
                          OFF_NW2, OFF_XW1, OFF_XW2, OFF_CW1, OFF_CW2};
    int b = blockIdx.x;
    const float* src = srcs[b];
    int K = Ks[b], off = offs[b];
    for (int idx = threadIdx.x; idx < K * 96; idx += 256) {
        int n = idx / K, k = idx - n * K;
        wsT[off + idx] = tobf(src[(size_t)k * 96 + n]);
    }
}

// ---------------- Kernel 1: edge_mlp -> ef (f32, into d_out ef2 region) ------
__global__ __launch_bounds__(256, 3) void k1_edge(
    const float* __restrict__ h, const int* __restrict__ eic,
    const float* __restrict__ ea, const short* __restrict__ wsT,
    const float* __restrict__ eb1, const float* __restrict__ eb2,
    float* __restrict__ efg) {
    __shared__ short xs[64 * 288];
    __shared__ short t1[64 * 96];
    const int t = threadIdx.x;
    const int e0 = blockIdx.x * 64;

    for (int idx = t; idx < 64 * 72; idx += 256) {
        int r = idx / 72, c = (idx - r * 72) * 4;
        int e = e0 + r;
        const float* src;
        if (c < 96)       src = &h[(size_t)(e >> 2) * 96 + c];
        else if (c < 192) src = &h[(size_t)eic[e] * 96 + (c - 96)];
        else              src = &ea[(size_t)e * 96 + (c - 192)];
        f4 v = *(const f4*)src;
        s4 b; b[0] = tobf(v[0]); b[1] = tobf(v[1]); b[2] = tobf(v[2]); b[3] = tobf(v[3]);
        *(s4*)&xs[(r * 288 + c) ^ ((r & 7) << 3)] = b;
    }
    __syncthreads();
    const int lane = t & 63, w = t >> 6;
    const int kg = lane >> 4, ln = lane & 15;
    const int r0 = w * 16;
    f4 acc[6];
    gemmNT<288, 6>(wsT + OFF_EW1, 0,
        [&](int ln_, int k0, int kg_) {
            int row = r0 + ln_;
            return *(const bf8*)&xs[(row * 288 + k0 + kg_ * 8) ^ ((row & 7) << 3)];
        }, acc);
#pragma unroll
    for (int nt = 0; nt < 6; nt++) {
        int col = nt * 16 + ln;
        float bia = eb1[col];
#pragma unroll
        for (int j = 0; j < 4; j++) {
            int row = r0 + kg * 4 + j;
            t1[(row * 96 + col) ^ ((row & 7) << 3)] = tobf(sp_f(acc[nt][j] + bia));
        }
    }
    __syncthreads();
    gemmNT<96, 6>(wsT + OFF_EW2, 0,
        [&](int ln_, int k0, int kg_) {
            int row = r0 + ln_;
            return *(const bf8*)&t1[(row * 96 + k0 + kg_ * 8) ^ ((row & 7) << 3)];
        }, acc);
#pragma unroll
    for (int nt = 0; nt < 6; nt++) {
        int col = nt * 16 + ln;
        float bia = eb2[col];
#pragma unroll
        for (int j = 0; j < 4; j++) {
            int row = r0 + kg * 4 + j;
            efg[(size_t)(e0 + row) * 96 + col] = sp_f(acc[nt][j] + bia);
        }
    }
}

// ---------------- Kernel 2: attention + node model -> hn ---------------------
__global__ __launch_bounds__(256, 3) void k2_attn(
    const float* __restrict__ h, const float* __restrict__ efg,
    const short* __restrict__ wsT,
    const float* __restrict__ qb, const float* __restrict__ kb,
    const float* __restrict__ vb,
    const float* __restrict__ nb1, const float* __restrict__ nb2,
    const float* __restrict__ g1, const float* __restrict__ be1,
    const float* __restrict__ g2, const float* __restrict__ be2,
    float* __restrict__ hng) {
    __shared__ short hsb[16 * 96];
    __shared__ short efs[64 * 96];
    __shared__ short qhb[16 * 96];
    __shared__ short kvb[64 * 96];   // kh, then vh
    __shared__ short agb[16 * 96];
    __shared__ short t1b[16 * 96];
    __shared__ float outb[16 * 96];
    __shared__ float sc[64 * 3];
    const int t = threadIdx.x;
    const int n0 = blockIdx.x * 16;
    const int e0 = n0 * 4;

    for (int idx = t; idx < 16 * 24; idx += 256) {
        int r = idx / 24, c = (idx - r * 24) * 4;
        f4 v = *(const f4*)&h[(size_t)(n0 + r) * 96 + c];
        s4 b; b[0] = tobf(v[0]); b[1] = tobf(v[1]); b[2] = tobf(v[2]); b[3] = tobf(v[3]);
        *(s4*)&hsb[(r * 96 + c) ^ ((r & 7) << 3)] = b;
    }
    for (int idx = t; idx < 64 * 24; idx += 256) {
        int r = idx / 24, c = (idx - r * 24) * 4;
        f4 v = *(const f4*)&efg[(size_t)(e0 + r) * 96 + c];
        s4 b; b[0] = tobf(v[0]); b[1] = tobf(v[1]); b[2] = tobf(v[2]); b[3] = tobf(v[3]);
        *(s4*)&efs[(r * 96 + c) ^ ((r & 7) << 3)] = b;
    }
    __syncthreads();
    const int lane = t & 63, w = t >> 6;
    const int kg = lane >> 4, ln = lane & 15;
    const int r0 = w * 16;
    // q projection: waves 0..2 own 2 n-tiles each (M = 16 nodes)
    if (w < 3) {
        f4 qa[2];
        gemmNT<96, 2>(wsT + OFF_QW, 2 * w,
            [&](int ln_, int k0, int kg_) {
                return *(const bf8*)&hsb[(ln_ * 96 + k0 + kg_ * 8) ^ ((ln_ & 7) << 3)];
            }, qa);
#pragma unroll
        for (int i = 0; i < 2; i++) {
            int col = (2 * w + i) * 16 + ln;
            float bia = qb[col];
#pragma unroll
            for (int j = 0; j < 4; j++) {
                int row = kg * 4 + j;
                qhb[(row * 96 + col) ^ ((row & 7) << 3)] = tobf(qa[i][j] + bia);
            }
        }
    }
    // kh: all waves, 16 edges each; input = concat[h[row], ef]
    {
        f4 acc[6];
        gemmNT<192, 6>(wsT + OFF_KW, 0,
            [&](int ln_, int k0, int kg_) {
                int e = r0 + ln_;
                if (k0 < 96) {
                    int row = e >> 2;
                    return *(const bf8*)&hsb[(row * 96 + k0 + kg_ * 8) ^ ((row & 7) << 3)];
                } else {
                    return *(const bf8*)&efs[(e * 96 + (k0 - 96) + kg_ * 8) ^ ((e & 7) << 3)];
                }
            }, acc);
#pragma unroll
        for (int nt = 0; nt < 6; nt++) {
            int col = nt * 16 + ln;
            float bia = kb[col];
#pragma unroll
            for (int j = 0; j < 4; j++) {
                int row = r0 + kg * 4 + j;
                kvb[(row * 96 + col) ^ ((row & 7) << 3)] = tobf(acc[nt][j] + bia);
            }
        }
    }
    __syncthreads();
    // scores: one thread per (edge, head), dot over d=32
    if (t < 192) {
        int e = t / 3, hd = t - e * 3;
        int nd = e >> 2;
        float s = 0.f;
#pragma unroll
        for (int c8 = 0; c8 < 4; c8++) {
            int c = hd * 32 + c8 * 8;
            bf8 qv = *(const bf8*)&qhb[(nd * 96 + c) ^ ((nd & 7) << 3)];
            bf8 kv = *(const bf8*)&kvb[(e * 96 + c) ^ ((e & 7) << 3)];
#pragma unroll
            for (int j = 0; j < 8; j++) s = fmaf(frombf(qv[j]), frombf(kv[j]), s);
        }
        sc[e * 3 + hd] = s * 0.17677669529663687f;   // 1/sqrt(32)
    }
    __syncthreads();
    // softmax over 4 edges per (node, head)
    if (t < 48) {
        int nd = t / 3, hd = t - nd * 3;
        float v0 = sc[(nd * 4 + 0) * 3 + hd], v1 = sc[(nd * 4 + 1) * 3 + hd];
        float v2 = sc[(nd * 4 + 2) * 3 + hd], v3 = sc[(nd * 4 + 3) * 3 + hd];
        float m = fmaxf(fmaxf(v0, v1), fmaxf(v2, v3));
        float p0 = __expf(v0 - m), p1 = __expf(v1 - m);
        float p2 = __expf(v2 - m), p3 = __expf(v3 - m);
        float inv = 1.f / (p0 + p1 + p2 + p3);
        sc[(nd * 4 + 0) * 3 + hd] = p0 * inv;
        sc[(nd * 4 + 1) * 3 + hd] = p1 * inv;
        sc[(nd * 4 + 2) * 3 + hd] = p2 * inv;
        sc[(nd * 4 + 3) * 3 + hd] = p3 * inv;
    }
    // vh: all waves (overwrites kvb; its readers done at the barrier above)
    {
        f4 acc[6];
        gemmNT<96, 6>(wsT + OFF_VW, 0,
            [&](int ln_, int k0, int kg_) {
                int e = r0 + ln_;
                return *(const bf8*)&efs[(e * 96 + k0 + kg_ * 8) ^ ((e & 7) << 3)];
            }, acc);
#pragma unroll
        for (int nt = 0; nt < 6; nt++) {
            int col = nt * 16 + ln;
            float bia = vb[col];
#pragma unroll
            for (int j = 0; j < 4; j++) {
                int row = r0 + kg * 4 + j;
                kvb[(row * 96 + col) ^ ((row & 7) << 3)] = tobf(acc[nt][j] + bia);
            }
        }
    }
    __syncthreads();
    // agg = sum_e attw * vh, LayerNorm(g1, be1) -> agb (bf16)
    {
        const int tx = t & 31, ty = t >> 5, c0 = tx * 3;
        for (int nd = ty; nd < 16; nd += 8) {
            float av[3];
#pragma unroll
            for (int j = 0; j < 3; j++) {
                int c = c0 + j, hd = c >> 5;
                float s = 0.f;
#pragma unroll
                for (int k = 0; k < 4; k++) {
                    int e = nd * 4 + k;
                    s = fmaf(sc[e * 3 + hd],
                             frombf(kvb[(e * 96 + c) ^ ((e & 7) << 3)]), s);
                }
                av[j] = s;
            }
            float ps = av[0] + av[1] + av[2];
            float ps2 = av[0] * av[0] + av[1] * av[1] + av[2] * av[2];
            for (int m = 1; m < 32; m <<= 1) {
                ps += __shfl_xor(ps, m);
                ps2 += __shfl_xor(ps2, m);
            }
            float mu = ps * (1.f / 96.f);
            float var = ps2 * (1.f / 96.f) - mu * mu;
            float rs = rsqrtf(var + 1e-5f);
#pragma unroll
            for (int j = 0; j < 3; j++) {
                int c = c0 + j;
                agb[(nd * 96 + c) ^ ((nd & 7) << 3)] =
                    tobf((av[j] - mu) * rs * g1[c] + be1[c]);
            }
        }
    }
    __syncthreads();
    // node MLP layer 1 (M=16, K=192): waves 0..2
    if (w < 3) {
        f4 a2[2];
        gemmNT<192, 2>(wsT + OFF_NW1, 2 * w,
            [&](int ln_, int k0, int kg_) {
                if (k0 < 96)
                    return *(const bf8*)&hsb[(ln_ * 96 + k0 + kg_ * 8) ^ ((ln_ & 7) << 3)];
                else
                    return *(const bf8*)&agb[(ln_ * 96 + (k0 - 96) + kg_ * 8) ^ ((ln_ & 7) << 3)];
            }, a2);
#pragma unroll
        for (int i = 0; i < 2; i++) {
            int col = (2 * w + i) * 16 + ln;
            float bia = nb1[col];
#pragma unroll
            for (int j = 0; j < 4; j++) {
                int row = kg * 4 + j;
                t1b[(row * 96 + col) ^ ((row & 7) << 3)] = tobf(sp_f(a2[i][j] + bia));
            }
        }
    }
    __syncthreads();
    // node MLP layer 2 + residual
    if (w < 3) {
        f4 a2[2];
        gemmNT<96, 2>(wsT + OFF_NW2, 2 * w,
            [&](int ln_, int k0, int kg_) {
                return *(const bf8*)&t1b[(ln_ * 96 + k0 + kg_ * 8) ^ ((ln_ & 7) << 3)];
            }, a2);
#pragma unroll
        for (int i = 0; i < 2; i++) {
            int col = (2 * w + i) * 16 + ln;
            float bia = nb2[col];
#pragma unroll
            for (int j = 0; j < 4; j++) {
                int row = kg * 4 + j;
                outb[row * 96 + col] = a2[i][j] + bia + h[(size_t)(n0 + row) * 96 + col];
            }
        }
    }
    __syncthreads();
    // LN2 -> hng
    {
        const int tx = t & 31, ty = t >> 5, c0 = tx * 3;
        for (int nd = ty; nd < 16; nd += 8) {
            float xv[3] = {outb[nd * 96 + c0], outb[nd * 96 + c0 + 1], outb[nd * 96 + c0 + 2]};
            float ps = xv[0] + xv[1] + xv[2];
            float ps2 = xv[0] * xv[0] + xv[1] * xv[1] + xv[2] * xv[2];
            for (int m = 1; m < 32; m <<= 1) {
                ps += __shfl_xor(ps, m);
                ps2 += __shfl_xor(ps2, m);
            }
            float mu = ps * (1.f / 96.f);
            float var = ps2 * (1.f / 96.f) - mu * mu;
            float rs = rsqrtf(var + 1e-5f);
#pragma unroll
            for (int j = 0; j < 3; j++) {
                int c = c0 + j;
                hng[(size_t)(n0 + nd) * 96 + c] = (xv[j] - mu) * rs * g2[c] + be2[c];
            }
        }
    }
}

// ---------------- Kernel 3: enhance (ef2) + coord MLP + acc ------------------
__global__ __launch_bounds__(256, 3) void k3_coord(
    const float* __restrict__ hng, const int* __restrict__ eic,
    const float* __restrict__ ea, const float* __restrict__ cp,
    const short* __restrict__ wsT,
    const float* __restrict__ xb1, const float* __restrict__ xb2,
    const float* __restrict__ cb1, const float* __restrict__ cb2,
    const float* __restrict__ cw3, const float* __restrict__ cb3,
    float* __restrict__ efg, float* __restrict__ accg) {
    __shared__ short xs[64 * 288];   // reused: A0=xs, A1=xs+6144, A2=xs+12288
    __shared__ short t1[64 * 96];
    __shared__ float cw3s[96 * 3];
    __shared__ float bcb[64 * 3];
    __shared__ float trs[64 * 4];
    const int t = threadIdx.x;
    const int e0 = blockIdx.x * 64;
    const int n0 = blockIdx.x * 16;

    for (int idx = t; idx < 64 * 72; idx += 256) {
        int r = idx / 72, c = (idx - r * 72) * 4;
        int e = e0 + r;
        const float* src;
        if (c < 96)       src = &hng[(size_t)(e >> 2) * 96 + c];
        else if (c < 192) src = &hng[(size_t)eic[e] * 96 + (c - 96)];
        else              src = &ea[(size_t)e * 96 + (c - 192)];
        f4 v = *(const f4*)src;
        s4 b; b[0] = tobf(v[0]); b[1] = tobf(v[1]); b[2] = tobf(v[2]); b[3] = tobf(v[3]);
        *(s4*)&xs[(r * 288 + c) ^ ((r & 7) << 3)] = b;
    }
    for (int idx = t; idx < 96 * 3; idx += 256) cw3s[idx] = cw3[idx];
    __syncthreads();
    const int lane = t & 63, w = t >> 6;
    const int kg = lane >> 4, ln = lane & 15;
    const int r0 = w * 16;
    f4 acc[6];
    // enhance layer 1 (K=288)
    gemmNT<288, 6>(wsT + OFF_XW1, 0,
        [&](int ln_, int k0, int kg_) {
            int row = r0 + ln_;
            return *(const bf8*)&xs[(row * 288 + k0 + kg_ * 8) ^ ((row & 7) << 3)];
        }, acc);
#pragma unroll
    for (int nt = 0; nt < 6; nt++) {
        int col = nt * 16 + ln;
        float bia = xb1[col];
#pragma unroll
        for (int j = 0; j < 4; j++) {
            int row = r0 + kg * 4 + j;
            t1[(row * 96 + col) ^ ((row & 7) << 3)] = tobf(sp_f(acc[nt][j] + bia));
        }
    }
    __syncthreads();
    // enhance layer 2 + residual ef -> ef2 (global) and A0 (bf16)
    short* A0 = xs;
    short* A1 = xs + 6144;
    short* A2 = xs + 12288;
    gemmNT<96, 6>(wsT + OFF_XW2, 0,
        [&](int ln_, int k0, int kg_) {
            int row = r0 + ln_;
            return *(const bf8*)&t1[(row * 96 + k0 + kg_ * 8) ^ ((row & 7) << 3)];
        }, acc);
#pragma unroll
    for (int nt = 0; nt < 6; nt++) {
        int col = nt * 16 + ln;
        float bia = xb2[col];
#pragma unroll
        for (int j = 0; j < 4; j++) {
            int row = r0 + kg * 4 + j;
            size_t gi = (size_t)(e0 + row) * 96 + col;
            float v = acc[nt][j] + bia + efg[gi];
            efg[gi] = v;
            A0[(row * 96 + col) ^ ((row & 7) << 3)] = tobf(v);
        }
    }
    __syncthreads();
    // coord MLP layer 1
    gemmNT<96, 6>(wsT + OFF_CW1, 0,
        [&](int ln_, int k0, int kg_) {
            int row = r0 + ln_;
            return *(const bf8*)&A0[(row * 96 + k0 + kg_ * 8) ^ ((row & 7) << 3)];
        }, acc);
#pragma unroll
    for (int nt = 0; nt < 6; nt++) {
        int col = nt * 16 + ln;
        float bia = cb1[col];
#pragma unroll
        for (int j = 0; j < 4; j++) {
            int row = r0 + kg * 4 + j;
            A1[(row * 96 + col) ^ ((row & 7) << 3)] = tobf(sp_f(acc[nt][j] + bia));
        }
    }
    __syncthreads();
    // coord MLP layer 2
    gemmNT<96, 6>(wsT + OFF_CW2, 0,
        [&](int ln_, int k0, int kg_) {
            int row = r0 + ln_;
            return *(const bf8*)&A1[(row * 96 + k0 + kg_ * 8) ^ ((row & 7) << 3)];
        }, acc);
#pragma unroll
    for (int nt = 0; nt < 6; nt++) {
        int col = nt * 16 + ln;
        float bia = cb2[col];
#pragma unroll
        for (int j = 0; j < 4; j++) {
            int row = r0 + kg * 4 + j;
            A2[(row * 96 + col) ^ ((row & 7) << 3)] = tobf(sp_f(acc[nt][j] + bia));
        }
    }
    __syncthreads();
    // bc = A2 @ cw3 + cb3 : one thread per (edge, component)
    if (t < 192) {
        int e = t / 3, j = t - e * 3;
        float s = cb3[j];
#pragma unroll
        for (int c8 = 0; c8 < 12; c8++) {
            bf8 av = *(const bf8*)&A2[(e * 96 + c8 * 8) ^ ((e & 7) << 3)];
#pragma unroll
            for (int jj = 0; jj < 8; jj++)
                s = fmaf(frombf(av[jj]), cw3s[(c8 * 8 + jj) * 3 + j], s);
        }
        bcb[e * 3 + j] = s;
    }
    __syncthreads();
    // geometry per edge
    if (t < 64) {
        int e = e0 + t;
        int rn = e >> 2, cn = eic[e];
        float r0c = cp[(size_t)rn * 3 + 0], r1c = cp[(size_t)rn * 3 + 1], r2c = cp[(size_t)rn * 3 + 2];
        float q0 = cp[(size_t)cn * 3 + 0], q1 = cp[(size_t)cn * 3 + 1], q2 = cp[(size_t)cn * 3 + 2];
        float d0 = r0c - q0, d1 = r1c - q1, d2 = r2c - q2;
        float x0 = r1c * q2 - r2c * q1;
        float x1 = r2c * q0 - r0c * q2;
        float x2 = r0c * q1 - r1c * q0;
        float v0 = d1 * x2 - d2 * x1;
        float v1 = d2 * x0 - d0 * x2;
        float v2 = d0 * x1 - d1 * x0;
        float b0 = bcb[t * 3 + 0], b1 = bcb[t * 3 + 1], b2 = bcb[t * 3 + 2];
        trs[t * 4 + 0] = fminf(fmaxf(d0 * b0 + x0 * b1 + v0 * b2, -100.f), 100.f);
        trs[t * 4 + 1] = fminf(fmaxf(d1 * b0 + x1 * b1 + v1 * b2, -100.f), 100.f);
        trs[t * 4 + 2] = fminf(fmaxf(d2 * b0 + x2 * b1 + v2 * b2, -100.f), 100.f);
    }
    __syncthreads();
    if (t < 48) {
        int nd = t / 3, j = t - nd * 3;
        float s = (trs[(nd * 4 + 0) * 4 + j] + trs[(nd * 4 + 1) * 4 + j] +
                   trs[(nd * 4 + 2) * 4 + j] + trs[(nd * 4 + 3) * 4 + j]) * 0.25f;
        accg[(size_t)(n0 + nd) * 3 + j] = s;
    }
}

extern "C" void kernel_launch(void* const* d_in, const int* in_sizes, int n_in,
                              void* d_out, int out_size, void* d_ws, size_t ws_size,
                              hipStream_t stream) {
    const float* h   = (const float*)d_in[0];
    const int*   ei  = (const int*)d_in[1];
    const float* cp  = (const float*)d_in[3];
    const float* ea  = (const float*)d_in[5];
    const float* ew1 = (const float*)d_in[6];
    const float* eb1 = (const float*)d_in[7];
    const float* ew2 = (const float*)d_in[8];
    const float* eb2 = (const float*)d_in[9];
    const float* xw1 = (const float*)d_in[10];
    const float* xb1 = (const float*)d_in[11];
    const float* xw2 = (const float*)d_in[12];
    const float* xb2 = (const float*)d_in[13];
    const float* nw1 = (const float*)d_in[14];
    const float* nb1 = (const float*)d_in[15];
    const float* nw2 = (const float*)d_in[16];
    const float* nb2 = (const float*)d_in[17];
    const float* cw1 = (const float*)d_in[18];
    const float* cb1 = (const float*)d_in[19];
    const float* cw2 = (const float*)d_in[20];
    const float* cb2 = (const float*)d_in[21];
    const float* cw3 = (const float*)d_in[22];
    const float* cb3 = (const float*)d_in[23];
    const float* qw  = (const float*)d_in[24];
    const float* qb  = (const float*)d_in[25];
    const float* kw  = (const float*)d_in[26];
    const float* kb  = (const float*)d_in[27];
    const float* vw  = (const float*)d_in[28];
    const float* vb  = (const float*)d_in[29];
    const float* g1  = (const float*)d_in[30];
    const float* be1 = (const float*)d_in[31];
    const float* g2  = (const float*)d_in[32];
    const float* be2 = (const float*)d_in[33];

    float* out  = (float*)d_out;
    float* accg = out;                                    // [NN,3]
    float* hng  = out + (size_t)NN * 3;                   // [NN,96]
    float* efg  = out + (size_t)NN * 3 + (size_t)NN * 96; // [NE,96] ef then ef2
    const int* eic = ei + NE;
    short* wsT = (short*)d_ws;                            // 313 KB of weights

    k_prep<<<11, 256, 0, stream>>>(ew1, ew2, kw, vw, qw, nw1, nw2, xw1, xw2,
                                   cw1, cw2, wsT);
    k1_edge<<<NE / 64, 256, 0, stream>>>(h, eic, ea, wsT, eb1, eb2, efg);
    k2_attn<<<NN / 16, 256, 0, stream>>>(h, efg, wsT, qb, kb, vb, nb1, nb2,
                                         g1, be1, g2, be2, hng);
    k3_coord<<<NE / 64, 256, 0, stream>>>(hng, eic, ea, cp, wsT, xb1, xb2,
                                          cb1, cb2, cw3, cb3, efg, accg);
}

// Round 5
// 440.761 us; speedup vs baseline: 10.1639x; 1.5933x over previous
//
#include <hip/hip_runtime.h>
#include <hip/hip_bf16.h>

#define B_GRAPHS 16384
#define NN (B_GRAPHS * 5)          // 81920 nodes
#define NE (NN * 4)                // 327680 edges
#define GPB 4                      // graphs per block
#define EPB 80                     // edges per block
#define NPB 20                     // nodes per block

typedef __attribute__((ext_vector_type(8))) short bf8;   // 8 x bf16
typedef __attribute__((ext_vector_type(4))) short s4;    // 4 x bf16
typedef __attribute__((ext_vector_type(4))) float f4;
typedef __attribute__((ext_vector_type(2))) unsigned u2;

// d_ws layout (bf16 elements) — all weights transposed to [N=96][K]
#define OFF_EW1 0
#define OFF_EW2 27648
#define OFF_KW  36864
#define OFF_VW  55296
#define OFF_QW  64512
#define OFF_NW1 73728
#define OFF_NW2 92160
#define OFF_XW1 101376
#define OFF_XW2 129024
#define OFF_CW1 138240
#define OFF_CW2 147456

__device__ __forceinline__ float sp_f(float x) {
    return fmaxf(x, 0.0f) + __logf(1.0f + __expf(-fabsf(x)));
}
__device__ __forceinline__ short tobf(float x) {
    return __builtin_bit_cast(short, __float2bfloat16(x));
}
__device__ __forceinline__ float frombf(short s) {
    union { float f; unsigned u; } v;
    v.u = ((unsigned)(unsigned short)s) << 16;
    return v.f;
}
__device__ __forceinline__ unsigned pk2(float a, float b) {
    unsigned lo = (unsigned short)tobf(a);
    unsigned hi = (unsigned short)tobf(b);
    return lo | (hi << 16);
}
// swizzled bf16 LDS frag read: row-major [rows][96], elem ^ ((row&7)<<3)
__device__ __forceinline__ bf8 ldfrag(const short* buf, int row, int k) {
    return *(const bf8*)&buf[(row * 96 + k) ^ ((row & 7) << 3)];
}
// pack 4 f32 -> 4 bf16 and store (8B) at swizzled addr (col0 multiple of 4)
__device__ __forceinline__ void stpk(short* buf, int row, int col0, f4 v) {
    u2 o = {pk2(v[0], v[1]), pk2(v[2], v[3])};
    *(u2*)&buf[(row * 96 + col0) ^ ((row & 7) << 3)] = o;
}

// Wave-owns-16-cols GEMM with swapped MFMA operands.
// acc[s][j] = out[row = s*16 + (lane&15)][col = wc0 + (lane>>4)*4 + j]
template <int K, int NS, class AF>
__device__ __forceinline__ void gemmCol(const short* __restrict__ wT, int wc0,
                                        int ln, int kg, AF aload, f4* acc) {
#pragma unroll
    for (int s = 0; s < NS; s++) {
        acc[s][0] = 0.f; acc[s][1] = 0.f; acc[s][2] = 0.f; acc[s][3] = 0.f;
    }
#pragma unroll
    for (int k0 = 0; k0 < K; k0 += 32) {
        bf8 wf = *(const bf8*)(wT + (size_t)(wc0 + ln) * K + k0 + kg * 8);
#pragma unroll
        for (int s = 0; s < NS; s++) {
            acc[s] = __builtin_amdgcn_mfma_f32_16x16x32_bf16(wf, aload(s, k0),
                                                             acc[s], 0, 0, 0);
        }
    }
}

// ---------------- Prep: transpose+convert weights into d_ws ------------------
__global__ __launch_bounds__(256) void k_prep(
    const float* ew1, const float* ew2, const float* kw, const float* vw,
    const float* qw, const float* nw1, const float* nw2, const float* xw1,
    const float* xw2, const float* cw1, const float* cw2, short* wsT) {
    const float* srcs[11] = {ew1, ew2, kw, vw, qw, nw1, nw2, xw1, xw2, cw1, cw2};
    const int Ks[11] = {288, 96, 192, 96, 96, 192, 96, 288, 96, 96, 96};
    const int offs[11] = {OFF_EW1, OFF_EW2, OFF_KW, OFF_VW, OFF_QW, OFF_NW1,
                          OFF_NW2, OFF_XW1, OFF_XW2, OFF_CW1, OFF_CW2};
    int b = blockIdx.x;
    const float* src = srcs[b];
    int K = Ks[b], off = offs[b];
    for (int idx = threadIdx.x; idx < K * 96; idx += 256) {
        int n = idx / K, k = idx - n * K;
        wsT[off + idx] = tobf(src[(size_t)k * 96 + n]);
    }
}

// ---------------- Fused: edge MLP + attention + node + enhance + coord -------
__global__ __launch_bounds__(384, 3) void k_fused(
    const float* __restrict__ h, const float* __restrict__ cp,
    const float* __restrict__ ea, const short* __restrict__ wsT,
    const float* __restrict__ eb1, const float* __restrict__ eb2,
    const float* __restrict__ qb, const float* __restrict__ kb,
    const float* __restrict__ vb, const float* __restrict__ nb1,
    const float* __restrict__ nb2, const float* __restrict__ g1,
    const float* __restrict__ be1, const float* __restrict__ g2,
    const float* __restrict__ be2, const float* __restrict__ xb1,
    const float* __restrict__ xb2, const float* __restrict__ cb1,
    const float* __restrict__ cb2, const float* __restrict__ cw3,
    const float* __restrict__ cb3,
    float* __restrict__ accg, float* __restrict__ hng, float* __restrict__ efg) {
    // LDS: 38976 shorts = 77,952 B. Overlays by lifetime (see offsets).
    __shared__ __align__(16) short smem[38976];
    short* hb  = smem;            // [20][96] h (bf16)   -> later hn (bf16)
    short* eab = smem + 1920;     // [80][96] edge_attr  (garbage-row spill target of hb)
    short* S1  = smem + 9600;     // [80][96] inter-layer scratch
    short* efb = smem + 17280;    // [80][96] ef -> later ef2 (A0)
    short* kvb = smem + 24960;    // [80][96] kh -> vh -> A2
    short* qag = smem + 32640;    // [20][96] qh -> agb  (spills into fscr: ok)
    float* fscr = (float*)(smem + 34560); // 1920 f32: sc | outb | bcb+trs
    float* cw3s = fscr + 1920;    // 288 f32

    const int t = threadIdx.x;
    const int blk = blockIdx.x;
    const int n0 = blk * NPB, e0 = blk * EPB;

    // ---- P0: stage inputs (bf16, swizzled) ----
    for (int i = t; i < 1920; i += 384) {
        int r = i / 24, c = (i - r * 24) * 4;
        f4 v = *(const f4*)&ea[(size_t)(e0 + r) * 96 + c];
        stpk(eab, r, c, v);
    }
    for (int i = t; i < 480; i += 384) {
        int r = i / 24, c = (i - r * 24) * 4;
        f4 v = *(const f4*)&h[(size_t)(n0 + r) * 96 + c];
        stpk(hb, r, c, v);
    }
    if (t < 288) cw3s[t] = cw3[t];
    __syncthreads();

    const int lane = t & 63, w = t >> 6;
    const int kg = lane >> 4, ln = lane & 15;
    const int wc0 = w * 16, col0 = wc0 + kg * 4;

    int erow[5], esrc[5], edst[5];
#pragma unroll
    for (int s = 0; s < 5; s++) {
        erow[s] = s * 16 + ln;
        int sl = erow[s] >> 2;
        esrc[s] = sl;
        int si = sl % 5, jj = erow[s] & 3;
        edst[s] = (sl / 5) * 5 + jj + (jj >= si);
    }

    f4 acc[5];
    // ---- P1: edge MLP L1 (K=288: [h[src], h[dst], ea]) -> S1 ----
    gemmCol<288, 5>(wsT + OFF_EW1, wc0, ln, kg,
        [&](int s, int k0) {
            int k = k0 + kg * 8;
            if (k0 < 96)  return ldfrag(hb, esrc[s], k);
            if (k0 < 192) return ldfrag(hb, edst[s], k - 96);
            return ldfrag(eab, erow[s], k - 192);
        }, acc);
    {
        f4 b = *(const f4*)&eb1[col0];
#pragma unroll
        for (int s = 0; s < 5; s++) {
            f4 v;
#pragma unroll
            for (int j = 0; j < 4; j++) v[j] = sp_f(acc[s][j] + b[j]);
            stpk(S1, erow[s], col0, v);
        }
    }
    __syncthreads();
    // ---- P2: edge MLP L2 (K=96) -> efb (ef) ----
    gemmCol<96, 5>(wsT + OFF_EW2, wc0, ln, kg,
        [&](int s, int k0) { return ldfrag(S1, erow[s], k0 + kg * 8); }, acc);
    {
        f4 b = *(const f4*)&eb2[col0];
#pragma unroll
        for (int s = 0; s < 5; s++) {
            f4 v;
#pragma unroll
            for (int j = 0; j < 4; j++) v[j] = sp_f(acc[s][j] + b[j]);
            stpk(efb, erow[s], col0, v);
        }
    }
    __syncthreads();
    // ---- P3: q proj (K=96, 2 node stripes) -> qag ; P4: kh (K=192) -> kvb ----
    {
        f4 qa[2];
        gemmCol<96, 2>(wsT + OFF_QW, wc0, ln, kg,
            [&](int s, int k0) { return ldfrag(hb, s * 16 + ln, k0 + kg * 8); }, qa);
        f4 b = *(const f4*)&qb[col0];
#pragma unroll
        for (int s = 0; s < 2; s++) {
            int row = s * 16 + ln;
            if (row < NPB) {
                f4 v;
#pragma unroll
                for (int j = 0; j < 4; j++) v[j] = qa[s][j] + b[j];
                stpk(qag, row, col0, v);
            }
        }
    }
    gemmCol<192, 5>(wsT + OFF_KW, wc0, ln, kg,
        [&](int s, int k0) {
            int k = k0 + kg * 8;
            if (k0 < 96) return ldfrag(hb, esrc[s], k);
            return ldfrag(efb, erow[s], k - 96);
        }, acc);
    {
        f4 b = *(const f4*)&kb[col0];
#pragma unroll
        for (int s = 0; s < 5; s++) {
            f4 v;
#pragma unroll
            for (int j = 0; j < 4; j++) v[j] = acc[s][j] + b[j];
            stpk(kvb, erow[s], col0, v);
        }
    }
    __syncthreads();
    // ---- P5a: scores (per edge x head) ----
    float* sc = fscr;   // 240 f32
    if (t < 240) {
        int e = t / 3, hd = t - e * 3, nd = e >> 2;
        float s = 0.f;
#pragma unroll
        for (int c8 = 0; c8 < 4; c8++) {
            int c = hd * 32 + c8 * 8;
            bf8 qv = ldfrag(qag, nd, c);
            bf8 kv = ldfrag(kvb, e, c);
#pragma unroll
            for (int j = 0; j < 8; j++) s = fmaf(frombf(qv[j]), frombf(kv[j]), s);
        }
        sc[e * 3 + hd] = s * 0.17677669529663687f;  // 1/sqrt(32)
    }
    __syncthreads();
    // ---- P5b: softmax over 4 edges ; P6: vh (K=96) -> kvb ----
    if (t < 60) {
        int nd = t / 3, hd = t - nd * 3;
        float v0 = sc[(nd * 4 + 0) * 3 + hd], v1 = sc[(nd * 4 + 1) * 3 + hd];
        float v2 = sc[(nd * 4 + 2) * 3 + hd], v3 = sc[(nd * 4 + 3) * 3 + hd];
        float m = fmaxf(fmaxf(v0, v1), fmaxf(v2, v3));
        float p0 = __expf(v0 - m), p1 = __expf(v1 - m);
        float p2 = __expf(v2 - m), p3 = __expf(v3 - m);
        float inv = 1.f / (p0 + p1 + p2 + p3);
        sc[(nd * 4 + 0) * 3 + hd] = p0 * inv;
        sc[(nd * 4 + 1) * 3 + hd] = p1 * inv;
        sc[(nd * 4 + 2) * 3 + hd] = p2 * inv;
        sc[(nd * 4 + 3) * 3 + hd] = p3 * inv;
    }
    gemmCol<96, 5>(wsT + OFF_VW, wc0, ln, kg,
        [&](int s, int k0) { return ldfrag(efb, erow[s], k0 + kg * 8); }, acc);
    {
        f4 b = *(const f4*)&vb[col0];
        __syncthreads();   // scores readers of kvb done (P5a barrier) + sc ready
#pragma unroll
        for (int s = 0; s < 5; s++) {
            f4 v;
#pragma unroll
            for (int j = 0; j < 4; j++) v[j] = acc[s][j] + b[j];
            stpk(kvb, erow[s], col0, v);
        }
    }
    __syncthreads();
    // ---- P7: agg = sum attw*vh ; LayerNorm1 -> qag (agb) ----
    {
        int tx = t & 31, ty = t >> 5, c0 = tx * 3;
        for (int nd = ty; nd < NPB; nd += 12) {
            float av[3];
#pragma unroll
            for (int j = 0; j < 3; j++) {
                int c = c0 + j, hd = c >> 5;
                float s = 0.f;
#pragma unroll
                for (int k = 0; k < 4; k++) {
                    int e = nd * 4 + k;
                    s = fmaf(sc[e * 3 + hd],
                             frombf(kvb[(e * 96 + c) ^ ((e & 7) << 3)]), s);
                }
                av[j] = s;
            }
            float ps = av[0] + av[1] + av[2];
            float ps2 = av[0] * av[0] + av[1] * av[1] + av[2] * av[2];
            for (int m = 1; m < 32; m <<= 1) {
                ps += __shfl_xor(ps, m);
                ps2 += __shfl_xor(ps2, m);
            }
            float mu = ps * (1.f / 96.f);
            float var = ps2 * (1.f / 96.f) - mu * mu;
            float rs = rsqrtf(var + 1e-5f);
#pragma unroll
            for (int j = 0; j < 3; j++) {
                int c = c0 + j;
                qag[(nd * 96 + c) ^ ((nd & 7) << 3)] =
                    tobf((av[j] - mu) * rs * g1[c] + be1[c]);
            }
        }
    }
    __syncthreads();
    // ---- P8: node MLP L1 (K=192: [h, agg]) -> S1 ----
    {
        f4 na[2];
        gemmCol<192, 2>(wsT + OFF_NW1, wc0, ln, kg,
            [&](int s, int k0) {
                int row = s * 16 + ln, k = k0 + kg * 8;
                if (k0 < 96) return ldfrag(hb, row, k);
                return ldfrag(qag, row, k - 96);
            }, na);
        f4 b = *(const f4*)&nb1[col0];
#pragma unroll
        for (int s = 0; s < 2; s++) {
            int row = s * 16 + ln;
            f4 v;
#pragma unroll
            for (int j = 0; j < 4; j++) v[j] = sp_f(na[s][j] + b[j]);
            stpk(S1, row, col0, v);   // garbage rows 20..31 harmless
        }
    }
    __syncthreads();
    // ---- P9: node MLP L2 (K=96) + residual h -> fscr (outb f32) ----
    {
        f4 na[2];
        gemmCol<96, 2>(wsT + OFF_NW2, wc0, ln, kg,
            [&](int s, int k0) { return ldfrag(S1, s * 16 + ln, k0 + kg * 8); }, na);
        f4 b = *(const f4*)&nb2[col0];
#pragma unroll
        for (int s = 0; s < 2; s++) {
            int row = s * 16 + ln;
            if (row < NPB) {
                f4 hv = *(const f4*)&h[(size_t)(n0 + row) * 96 + col0];
                f4 v;
#pragma unroll
                for (int j = 0; j < 4; j++) v[j] = na[s][j] + b[j] + hv[j];
                *(f4*)&fscr[row * 96 + col0] = v;
            }
        }
    }
    __syncthreads();
    // ---- P10: LayerNorm2 -> hng global + hb (hn bf16) ----
    {
        int tx = t & 31, ty = t >> 5, c0 = tx * 3;
        for (int nd = ty; nd < NPB; nd += 12) {
            float xv[3] = {fscr[nd * 96 + c0], fscr[nd * 96 + c0 + 1],
                           fscr[nd * 96 + c0 + 2]};
            float ps = xv[0] + xv[1] + xv[2];
            float ps2 = xv[0] * xv[0] + xv[1] * xv[1] + xv[2] * xv[2];
            for (int m = 1; m < 32; m <<= 1) {
                ps += __shfl_xor(ps, m);
                ps2 += __shfl_xor(ps2, m);
            }
            float mu = ps * (1.f / 96.f);
            float var = ps2 * (1.f / 96.f) - mu * mu;
            float rs = rsqrtf(var + 1e-5f);
#pragma unroll
            for (int j = 0; j < 3; j++) {
                int c = c0 + j;
                float o = (xv[j] - mu) * rs * g2[c] + be2[c];
                hng[(size_t)(n0 + nd) * 96 + c] = o;
                hb[(nd * 96 + c) ^ ((nd & 7) << 3)] = tobf(o);
            }
        }
    }
    __syncthreads();
    // ---- P11: enhance L1 (K=288: [hn[src], hn[dst], ea]) -> S1 ----
    gemmCol<288, 5>(wsT + OFF_XW1, wc0, ln, kg,
        [&](int s, int k0) {
            int k = k0 + kg * 8;
            if (k0 < 96)  return ldfrag(hb, esrc[s], k);
            if (k0 < 192) return ldfrag(hb, edst[s], k - 96);
            return ldfrag(eab, erow[s], k - 192);
        }, acc);
    {
        f4 b = *(const f4*)&xb1[col0];
#pragma unroll
        for (int s = 0; s < 5; s++) {
            f4 v;
#pragma unroll
            for (int j = 0; j < 4; j++) v[j] = sp_f(acc[s][j] + b[j]);
            stpk(S1, erow[s], col0, v);
        }
    }
    __syncthreads();
    // ---- P12: enhance L2 (K=96) + ef residual -> efg global + efb (A0) ----
    gemmCol<96, 5>(wsT + OFF_XW2, wc0, ln, kg,
        [&](int s, int k0) { return ldfrag(S1, erow[s], k0 + kg * 8); }, acc);
    {
        f4 b = *(const f4*)&xb2[col0];
#pragma unroll
        for (int s = 0; s < 5; s++) {
            int row = erow[s];
            s4 ev = *(const s4*)&efb[(row * 96 + col0) ^ ((row & 7) << 3)];
            f4 v;
#pragma unroll
            for (int j = 0; j < 4; j++) v[j] = acc[s][j] + b[j] + frombf(ev[j]);
            *(f4*)&efg[(size_t)(e0 + row) * 96 + col0] = v;
            stpk(efb, row, col0, v);
        }
    }
    __syncthreads();
    // ---- P13: coord MLP L1 (K=96) -> S1 ----
    gemmCol<96, 5>(wsT + OFF_CW1, wc0, ln, kg,
        [&](int s, int k0) { return ldfrag(efb, erow[s], k0 + kg * 8); }, acc);
    {
        f4 b = *(const f4*)&cb1[col0];
#pragma unroll
        for (int s = 0; s < 5; s++) {
            f4 v;
#pragma unroll
            for (int j = 0; j < 4; j++) v[j] = sp_f(acc[s][j] + b[j]);
            stpk(S1, erow[s], col0, v);
        }
    }
    __syncthreads();
    // ---- P14: coord MLP L2 (K=96) -> kvb (A2) ----
    gemmCol<96, 5>(wsT + OFF_CW2, wc0, ln, kg,
        [&](int s, int k0) { return ldfrag(S1, erow[s], k0 + kg * 8); }, acc);
    {
        f4 b = *(const f4*)&cb2[col0];
#pragma unroll
        for (int s = 0; s < 5; s++) {
            f4 v;
#pragma unroll
            for (int j = 0; j < 4; j++) v[j] = sp_f(acc[s][j] + b[j]);
            stpk(kvb, erow[s], col0, v);
        }
    }
    __syncthreads();
    // ---- P15: bc = A2 @ cw3 + cb3 -> fscr[0..239] ----
    if (t < 240) {
        int e = t / 3, j = t - e * 3;
        float s = cb3[j];
#pragma unroll
        for (int c8 = 0; c8 < 12; c8++) {
            bf8 av = ldfrag(kvb, e, c8 * 8);
#pragma unroll
            for (int jj = 0; jj < 8; jj++)
                s = fmaf(frombf(av[jj]), cw3s[(c8 * 8 + jj) * 3 + j], s);
        }
        fscr[e * 3 + j] = s;
    }
    __syncthreads();
    // ---- P16: geometry per edge -> fscr[256..575] (trs) ----
    if (t < 80) {
        int sl = t >> 2, jj = t & 3, si = sl % 5;
        int dl = (sl / 5) * 5 + jj + (jj >= si);
        int rn = n0 + sl, cn = n0 + dl;
        float r0c = cp[(size_t)rn * 3 + 0], r1c = cp[(size_t)rn * 3 + 1],
              r2c = cp[(size_t)rn * 3 + 2];
        float q0 = cp[(size_t)cn * 3 + 0], q1 = cp[(size_t)cn * 3 + 1],
              q2 = cp[(size_t)cn * 3 + 2];
        float d0 = r0c - q0, d1 = r1c - q1, d2 = r2c - q2;
        float x0 = r1c * q2 - r2c * q1;
        float x1 = r2c * q0 - r0c * q2;
        float x2 = r0c * q1 - r1c * q0;
        float v0 = d1 * x2 - d2 * x1;
        float v1 = d2 * x0 - d0 * x2;
        float v2 = d0 * x1 - d1 * x0;
        float b0 = fscr[t * 3 + 0], b1 = fscr[t * 3 + 1], b2 = fscr[t * 3 + 2];
        fscr[256 + t * 4 + 0] = fminf(fmaxf(d0 * b0 + x0 * b1 + v0 * b2, -100.f), 100.f);
        fscr[256 + t * 4 + 1] = fminf(fmaxf(d1 * b0 + x1 * b1 + v1 * b2, -100.f), 100.f);
        fscr[256 + t * 4 + 2] = fminf(fmaxf(d2 * b0 + x2 * b1 + v2 * b2, -100.f), 100.f);
    }
    __syncthreads();
    // ---- P17: acc = mean over each node's 4 edges ----
    if (t < 60) {
        int nd = t / 3, j = t - nd * 3;
        float s = (fscr[256 + (nd * 4 + 0) * 4 + j] + fscr[256 + (nd * 4 + 1) * 4 + j] +
                   fscr[256 + (nd * 4 + 2) * 4 + j] + fscr[256 + (nd * 4 + 3) * 4 + j]) *
                  0.25f;
        accg[(size_t)(n0 + nd) * 3 + j] = s;
    }
}

extern "C" void kernel_launch(void* const* d_in, const int* in_sizes, int n_in,
                              void* d_out, int out_size, void* d_ws, size_t ws_size,
                              hipStream_t stream) {
    const float* h   = (const float*)d_in[0];
    const float* cp  = (const float*)d_in[3];   // coord_pre
    const float* ea  = (const float*)d_in[5];   // edge_attr
    const float* ew1 = (const float*)d_in[6];
    const float* eb1 = (const float*)d_in[7];
    const float* ew2 = (const float*)d_in[8];
    const float* eb2 = (const float*)d_in[9];
    const float* xw1 = (const float*)d_in[10];
    const float* xb1 = (const float*)d_in[11];
    const float* xw2 = (const float*)d_in[12];
    const float* xb2 = (const float*)d_in[13];
    const float* nw1 = (const float*)d_in[14];
    const float* nb1 = (const float*)d_in[15];
    const float* nw2 = (const float*)d_in[16];
    const float* nb2 = (const float*)d_in[17];
    const float* cw1 = (const float*)d_in[18];
    const float* cb1 = (const float*)d_in[19];
    const float* cw2 = (const float*)d_in[20];
    const float* cb2 = (const float*)d_in[21];
    const float* cw3 = (const float*)d_in[22];
    const float* cb3 = (const float*)d_in[23];
    const float* qw  = (const float*)d_in[24];
    const float* qb  = (const float*)d_in[25];
    const float* kw  = (const float*)d_in[26];
    const float* kb  = (const float*)d_in[27];
    const float* vw  = (const float*)d_in[28];
    const float* vb  = (const float*)d_in[29];
    const float* g1  = (const float*)d_in[30];
    const float* be1 = (const float*)d_in[31];
    const float* g2  = (const float*)d_in[32];
    const float* be2 = (const float*)d_in[33];

    float* out  = (float*)d_out;
    float* accg = out;                                    // [NN,3]
    float* hng  = out + (size_t)NN * 3;                   // [NN,96]
    float* efg  = out + (size_t)NN * 3 + (size_t)NN * 96; // [NE,96] ef2
    short* wsT = (short*)d_ws;                            // 313 KB of weights

    k_prep<<<11, 256, 0, stream>>>(ew1, ew2, kw, vw, qw, nw1, nw2, xw1, xw2,
                                   cw1, cw2, wsT);
    k_fused<<<B_GRAPHS / GPB, 384, 0, stream>>>(
        h, cp, ea, wsT, eb1, eb2, qb, kb, vb, nb1, nb2, g1, be1, g2, be2,
        xb1, xb2, cb1, cb2, cw3, cb3, accg, hng, efg);
}